// Round 11
// baseline (119.950 us; speedup 1.0000x reference)
//
#include <hip/hip_runtime.h>

#define BB 2
#define NN 512
#define MM 512
#define DD 128
#define HH 256

// ---------------------------------------------------------------------------
// K1: hx[g,h] = X[g,:]@W1x[:,h] + b1[h];  hy[g,h] = Y[g,:]@W1y[:,h]
//     (g = global row b*N+n, resp b*M+m)
//     + mask(int) -> mf(float)   + cntv[g] = sum_m mask[g,m]
// grid 512 x 256 (2 blocks/CU). Row operands are block-uniform -> s_load.
// ---------------------------------------------------------------------------
__global__ __launch_bounds__(256) void k_inproj(
    const float* __restrict__ X, const float* __restrict__ Y,
    const float* __restrict__ W1x, const float* __restrict__ W1y,
    const float* __restrict__ b1, const int* __restrict__ mask,
    float* __restrict__ hx, float* __restrict__ hy,
    float* __restrict__ mf, float* __restrict__ cntv)
{
    int blk = blockIdx.x, t = threadIdx.x;

    // mask -> float: 131072 int4 total / 512 blocks = 256 int4/block
    {
        int idx = blk * 256 + t;
        int4 v = ((const int4*)mask)[idx];
        ((float4*)mf)[idx] = make_float4((float)v.x, (float)v.y,
                                         (float)v.z, (float)v.w);
    }

    bool isX = blk < 256;
    const float* src = isX ? X : Y;
    const float* W   = isX ? W1x : W1y;
    float* dst       = isX ? hx : hy;
    int row0 = (isX ? blk : blk - 256) * 4;      // global row (covers both b)

    if (isX) {   // per-row mask counts for rows row0..row0+3
        int wave = t >> 6, lane = t & 63;
        const int* mrow = mask + (size_t)(row0 + wave) * MM;
        int c = 0;
#pragma unroll
        for (int k = 0; k < 8; ++k) c += mrow[lane + k * 64];
#pragma unroll
        for (int off = 32; off; off >>= 1) c += __shfl_down(c, off);
        if (lane == 0) cntv[row0 + wave] = (float)c;
    }

    const float* r0 = src + (size_t)row0 * DD;
    float bias = isX ? b1[t] : 0.0f;
    float a0 = bias, a1 = bias, a2 = bias, a3 = bias;

#pragma unroll 16
    for (int d = 0; d < DD; ++d) {
        float w = W[(size_t)d * HH + t];         // vector load, coalesced
        a0 = fmaf(r0[d         ], w, a0);        // uniform -> s_load
        a1 = fmaf(r0[d +   DD  ], w, a1);
        a2 = fmaf(r0[d + 2 * DD], w, a2);
        a3 = fmaf(r0[d + 3 * DD], w, a3);
    }
    dst[(size_t)(row0 + 0) * HH + t] = a0;
    dst[(size_t)(row0 + 1) * HH + t] = a1;
    dst[(size_t)(row0 + 2) * HH + t] = a2;
    dst[(size_t)(row0 + 3) * HH + t] = a3;
}

// ---------------------------------------------------------------------------
// K2: fused per 4-row n-tile. grid 256 x 1024 (16 waves/CU = 4 waves/SIMD).
//  B: S[r][h] = sum_m mf*relu(hx+hy); m 4-way split (mq = t>>8), 128 iters,
//     masks via s_load (scalar pipe) -> ZERO LDS in the hot loop
//  C: Zpre = X + S@W2 + cnt*b2 (8-way split-k, 32 iters); LN0 -> znT[d][r]
//  D: u = relu(zn@Wf1+bf1) (4-way d-split, 32 iters)
//  E: Z2 = zn + u@Wf2 + bf2 (8-way split-k); LN1 -> out
// ---------------------------------------------------------------------------
__global__ __launch_bounds__(1024) void k_fused(
    const float* __restrict__ X, const float* __restrict__ hx,
    const float* __restrict__ hy, const float* __restrict__ mf,
    const float* __restrict__ cntv,
    const float* __restrict__ W2, const float* __restrict__ b2,
    const float* __restrict__ Wf1, const float* __restrict__ bf1,
    const float* __restrict__ Wf2, const float* __restrict__ bf2,
    const float* __restrict__ g0, const float* __restrict__ be0,
    const float* __restrict__ g1, const float* __restrict__ be1,
    float* __restrict__ out)
{
    __shared__ float sSp[4][4][HH];     // 16 KB [mq][r][h] partial S
    __shared__ float sST[4][HH];        //  4 KB [r][h] merged S
    __shared__ float scratch[8][4][DD]; // 16 KB [q][r][d] split-k partials
    __shared__ float znT[DD][4];        //  2 KB [d][r] LN0 out (float4/d)
    __shared__ float sp2[4][4][HH];     // 16 KB [dq][r][h] FF1 partials
    __shared__ float suT[4][HH];        //  4 KB [r][h] relu'd hidden
    __shared__ float srow[4][DD];       //  2 KB LN workspace

    int t = threadIdx.x;
    int grow0 = blockIdx.x * 4;          // global row (b*N + n0)
    int b = grow0 >> 9;

    // ---- Phase B: masked-relu reduction, m-quarter mq
    {
        int h = t & 255, mq = t >> 8;
        float hxv[4];
#pragma unroll
        for (int r = 0; r < 4; ++r)
            hxv[r] = hx[(size_t)(grow0 + r) * HH + h];
        const float* hyp = hy + ((size_t)(b * MM) + mq * 128) * HH + h;
        const float* mfp = mf + (size_t)grow0 * MM + mq * 128;
        float a0 = 0.f, a1 = 0.f, a2 = 0.f, a3 = 0.f;
#pragma unroll 8
        for (int m = 0; m < 128; ++m) {
            float hyv = hyp[(size_t)m * HH];        // vector, L2 hit
            float w0 = mfp[m         ];             // uniform -> s_load
            float w1 = mfp[m +     MM];
            float w2 = mfp[m + 2 * MM];
            float w3 = mfp[m + 3 * MM];
            a0 = fmaf(fmaxf(hxv[0] + hyv, 0.f), w0, a0);
            a1 = fmaf(fmaxf(hxv[1] + hyv, 0.f), w1, a1);
            a2 = fmaf(fmaxf(hxv[2] + hyv, 0.f), w2, a2);
            a3 = fmaf(fmaxf(hxv[3] + hyv, 0.f), w3, a3);
        }
        sSp[mq][0][h] = a0; sSp[mq][1][h] = a1;
        sSp[mq][2][h] = a2; sSp[mq][3][h] = a3;
    }
    __syncthreads();
    {   // merge 4 m-quarters: 1024 threads = (r,h)
        int r = t >> 8, h = t & 255;
        sST[r][h] = sSp[0][r][h] + sSp[1][r][h] + sSp[2][r][h] + sSp[3][r][h];
    }
    __syncthreads();

    // ---- Phase C: Zpre = X + S@W2 + cnt*b2, LN0
    {
        int d = t & 127, q = t >> 7;     // q in 0..7 (h-eighth)
        int hb = q * 32;
        const float* wp = W2 + (size_t)hb * DD + d;
        float a0 = 0.f, a1 = 0.f, a2 = 0.f, a3 = 0.f;
#pragma unroll 8
        for (int hh = 0; hh < 32; ++hh) {
            float w = wp[(size_t)hh * DD];
            a0 = fmaf(sST[0][hb + hh], w, a0);      // b32 broadcast
            a1 = fmaf(sST[1][hb + hh], w, a1);
            a2 = fmaf(sST[2][hb + hh], w, a2);
            a3 = fmaf(sST[3][hb + hh], w, a3);
        }
        scratch[q][0][d] = a0; scratch[q][1][d] = a1;
        scratch[q][2][d] = a2; scratch[q][3][d] = a3;
    }
    __syncthreads();
    if (t < 512) {
        int r = t >> 7, d = t & 127;
        float s = scratch[0][r][d] + scratch[1][r][d]
                + scratch[2][r][d] + scratch[3][r][d]
                + scratch[4][r][d] + scratch[5][r][d]
                + scratch[6][r][d] + scratch[7][r][d];
        srow[r][d] = s + X[(size_t)(grow0 + r) * DD + d]
                   + cntv[grow0 + r] * b2[d];
    }
    __syncthreads();
    if (t < 256) {                        // LN0: wave w -> row w
        int wave = t >> 6, lane = t & 63;
        float v0 = srow[wave][lane], v1 = srow[wave][lane + 64];
        float s = v0 + v1, q2 = v0 * v0 + v1 * v1;
#pragma unroll
        for (int off = 32; off; off >>= 1) {
            s += __shfl_down(s, off); q2 += __shfl_down(q2, off);
        }
        s = __shfl(s, 0); q2 = __shfl(q2, 0);
        float mu   = s * (1.0f / 128.0f);
        float var  = q2 * (1.0f / 128.0f) - mu * mu;
        float rstd = rsqrtf(var + 1e-5f);
        znT[lane][wave]      = (v0 - mu) * rstd * g0[lane]      + be0[lane];
        znT[lane + 64][wave] = (v1 - mu) * rstd * g0[lane + 64] + be0[lane + 64];
    }
    __syncthreads();

    // ---- Phase D: u = relu(zn@Wf1 + bf1), d-quarter dq
    {
        int h = t & 255, dq = t >> 8;
        int db = dq * 32;
        float bias = (dq == 0) ? bf1[h] : 0.f;
        float a0 = bias, a1 = bias, a2 = bias, a3 = bias;
        const float* wp = Wf1 + (size_t)db * HH + h;
#pragma unroll 8
        for (int dd = 0; dd < 32; ++dd) {
            float w = wp[(size_t)dd * HH];
            float4 z4 = *(const float4*)&znT[db + dd][0];   // b128 broadcast
            a0 = fmaf(z4.x, w, a0); a1 = fmaf(z4.y, w, a1);
            a2 = fmaf(z4.z, w, a2); a3 = fmaf(z4.w, w, a3);
        }
        sp2[dq][0][h] = a0; sp2[dq][1][h] = a1;
        sp2[dq][2][h] = a2; sp2[dq][3][h] = a3;
    }
    __syncthreads();
    {
        int r = t >> 8, h = t & 255;
        suT[r][h] = fmaxf(sp2[0][r][h] + sp2[1][r][h]
                        + sp2[2][r][h] + sp2[3][r][h], 0.f);
    }
    __syncthreads();

    // ---- Phase E: Z2 = zn + u@Wf2 + bf2, LN1 -> out
    {
        int d = t & 127, q = t >> 7;
        int hb = q * 32;
        const float* wp = Wf2 + (size_t)hb * DD + d;
        float a0 = 0.f, a1 = 0.f, a2 = 0.f, a3 = 0.f;
#pragma unroll 8
        for (int hh = 0; hh < 32; ++hh) {
            float w = wp[(size_t)hh * DD];
            a0 = fmaf(suT[0][hb + hh], w, a0);
            a1 = fmaf(suT[1][hb + hh], w, a1);
            a2 = fmaf(suT[2][hb + hh], w, a2);
            a3 = fmaf(suT[3][hb + hh], w, a3);
        }
        scratch[q][0][d] = a0; scratch[q][1][d] = a1;
        scratch[q][2][d] = a2; scratch[q][3][d] = a3;
    }
    __syncthreads();
    if (t < 512) {
        int r = t >> 7, d = t & 127;
        float s = scratch[0][r][d] + scratch[1][r][d]
                + scratch[2][r][d] + scratch[3][r][d]
                + scratch[4][r][d] + scratch[5][r][d]
                + scratch[6][r][d] + scratch[7][r][d];
        srow[r][d] = znT[d][r] + s + bf2[d];
    }
    __syncthreads();
    if (t < 256) {                        // LN1: wave w -> row w
        int wave = t >> 6, lane = t & 63;
        float v0 = srow[wave][lane], v1 = srow[wave][lane + 64];
        float s = v0 + v1, q2 = v0 * v0 + v1 * v1;
#pragma unroll
        for (int off = 32; off; off >>= 1) {
            s += __shfl_down(s, off); q2 += __shfl_down(q2, off);
        }
        s = __shfl(s, 0); q2 = __shfl(q2, 0);
        float mu   = s * (1.0f / 128.0f);
        float var  = q2 * (1.0f / 128.0f) - mu * mu;
        float rstd = rsqrtf(var + 1e-5f);
        size_t row = (size_t)(grow0 + wave) * DD;
        out[row + lane]      = (v0 - mu) * rstd * g1[lane]      + be1[lane];
        out[row + lane + 64] = (v1 - mu) * rstd * g1[lane + 64] + be1[lane + 64];
    }
}

// ---------------------------------------------------------------------------
extern "C" void kernel_launch(void* const* d_in, const int* in_sizes, int n_in,
                              void* d_out, int out_size, void* d_ws, size_t ws_size,
                              hipStream_t stream)
{
    const float* X    = (const float*)d_in[0];
    const float* Y    = (const float*)d_in[1];
    const int*   mask = (const int*)d_in[2];
    const float* W1y  = (const float*)d_in[3];
    const float* W1x  = (const float*)d_in[4];
    const float* b1   = (const float*)d_in[5];
    const float* W2   = (const float*)d_in[6];
    const float* b2   = (const float*)d_in[7];
    const float* Wf1  = (const float*)d_in[8];
    const float* bf1  = (const float*)d_in[9];
    const float* Wf2  = (const float*)d_in[10];
    const float* bf2  = (const float*)d_in[11];
    const float* g0   = (const float*)d_in[12];
    const float* be0  = (const float*)d_in[13];
    const float* g1   = (const float*)d_in[14];
    const float* be1  = (const float*)d_in[15];
    float* out = (float*)d_out;

    // workspace (floats): hx[1MB] | hy[1MB] | mf[2MB] | cntv[4KB]
    float* ws   = (float*)d_ws;
    float* hx   = ws;
    float* hy   = hx + (size_t)BB * NN * HH;
    float* mf   = hy + (size_t)BB * MM * HH;
    float* cntv = mf + (size_t)BB * NN * MM;

    k_inproj<<<512, 256, 0, stream>>>(X, Y, W1x, W1y, b1, mask,
                                      hx, hy, mf, cntv);
    k_fused <<<256, 1024, 0, stream>>>(X, hx, hy, mf, cntv, W2, b2, Wf1, bf1,
                                       Wf2, bf2, g0, be0, g1, be1, out);
}